// Round 1
// baseline (716.747 us; speedup 1.0000x reference)
//
#include <hip/hip_runtime.h>
#include <hip/hip_bf16.h>

#define N_ENT  100000
#define N_REL2 1000
#define H      256
#define E_EDGES 320000

typedef unsigned short u16;
typedef short bf16x8 __attribute__((ext_vector_type(8)));
typedef float floatx4 __attribute__((ext_vector_type(4)));

__device__ __forceinline__ u16 f2bf(float f) {
    unsigned x = __float_as_uint(f);
    unsigned r = (x + 0x7fffu + ((x >> 16) & 1u)) >> 16;  // RNE
    return (u16)r;
}

__device__ __forceinline__ ushort4 pack4(float4 v, float s) {
    return make_ushort4(f2bf(v.x * s), f2bf(v.y * s), f2bf(v.z * s), f2bf(v.w * s));
}

// ---------------- CSR build ----------------

__global__ void hist_kernel(const int* __restrict__ dst, int* __restrict__ counts) {
    int i = blockIdx.x * blockDim.x + threadIdx.x;
    if (i < E_EDGES) atomicAdd(&counts[dst[i]], 1);
}

// single-block exclusive scan over counts -> offsets (N_ENT+1 entries)
__global__ void scan_kernel(const int* __restrict__ counts, int* __restrict__ offsets) {
    __shared__ int buf[1024];
    __shared__ int carry;
    int tid = threadIdx.x;
    if (tid == 0) carry = 0;
    __syncthreads();
    for (int base = 0; base < N_ENT; base += 1024) {
        int i = base + tid;
        int v = (i < N_ENT) ? counts[i] : 0;
        buf[tid] = v;
        __syncthreads();
        int c = carry;
        for (int off = 1; off < 1024; off <<= 1) {
            int t = (tid >= off) ? buf[tid - off] : 0;
            __syncthreads();
            buf[tid] += t;
            __syncthreads();
        }
        if (i < N_ENT) offsets[i] = c + buf[tid] - v;  // exclusive
        __syncthreads();
        if (tid == 0) carry = c + buf[1023];
        __syncthreads();
    }
    if (tid == 0) offsets[N_ENT] = carry;
}

__global__ void place_kernel(const int* __restrict__ dst, const int* __restrict__ offsets,
                             int* __restrict__ counts, int* __restrict__ sorted) {
    int i = blockIdx.x * blockDim.x + threadIdx.x;
    if (i < E_EDGES) {
        int d = dst[i];
        int old = atomicSub(&counts[d], 1);
        sorted[offsets[d] + old - 1] = i;
    }
}

// ---------------- weight prep ----------------
// Swizzle W[k][n] (row-major 256x256 fp32) into B-fragment order for
// mfma_f32_16x16x32_bf16: dst[((ntile*8+kstep)*64+lane)*8+j] =
//   bf16(W[kstep*32 + (lane>>4)*8 + j][ntile*16 + (lane&15)])
__global__ void swz_kernel(const float* __restrict__ w0, const float* __restrict__ w1,
                           const float* __restrict__ w2, const float* __restrict__ w3,
                           u16* __restrict__ dstp) {
    int t = blockIdx.x * blockDim.x + threadIdx.x;
    if (t >= 4 * H * H) return;
    int mat = t >> 16;
    int r = t & 65535;
    int j = r & 7, lane = (r >> 3) & 63, kstep = (r >> 9) & 7, ntile = r >> 12;
    int k = kstep * 32 + (lane >> 4) * 8 + j;
    int n = ntile * 16 + (lane & 15);
    const float* W = (mat == 0) ? w0 : (mat == 1) ? w1 : (mat == 2) ? w2 : w3;
    dstp[t] = f2bf(W[k * H + n]);
}

__global__ void relbf_kernel(const float* __restrict__ rel, u16* __restrict__ out) {
    int t = blockIdx.x * blockDim.x + threadIdx.x;
    if (t < N_REL2 * H) out[t] = f2bf(rel[t]);
}

// ---------------- per-destination fused scores + softmax + segment-sum ----------------
// one wave (64 lanes) per destination node; online softmax; fp32 register accumulation
__global__ void scatter_kernel(const float* __restrict__ ent, const float* __restrict__ rel,
                               const int* __restrict__ src, const int* __restrict__ rel_id,
                               const int* __restrict__ node_id,
                               const int* __restrict__ offsets, const int* __restrict__ sorted,
                               u16* __restrict__ agg_e, u16* __restrict__ agg_n,
                               u16* __restrict__ agg_c) {
    int d = blockIdx.x * 4 + (threadIdx.x >> 6);
    int lane = threadIdx.x & 63;
    if (d >= N_ENT) return;
    int nid = node_id[d];
    float4 hd = ((const float4*)(ent + (size_t)nid * H))[lane];
    int p0 = offsets[d], p1 = offsets[d + 1];
    float me = -INFINITY, mn = -INFINITY, mc = -INFINITY;
    float le = 0.f, ln = 0.f, lc = 0.f;
    float4 ae = make_float4(0, 0, 0, 0), an = make_float4(0, 0, 0, 0), ac = make_float4(0, 0, 0, 0);
    for (int p = p0; p < p1; ++p) {
        int ei = sorted[p];
        int sid = node_id[src[ei]];
        int rid = rel_id[ei];
        float4 ev = ((const float4*)(rel + (size_t)rid * H))[lane];
        float4 sv = ((const float4*)(ent + (size_t)sid * H))[lane];
        float4 cv = make_float4(ev.x * sv.x, ev.y * sv.y, ev.z * sv.z, ev.w * sv.w);
        float de = ev.x * hd.x + ev.y * hd.y + ev.z * hd.z + ev.w * hd.w;
        float dn = sv.x * hd.x + sv.y * hd.y + sv.z * hd.z + sv.w * hd.w;
        float dc = cv.x * hd.x + cv.y * hd.y + cv.z * hd.z + cv.w * hd.w;
#pragma unroll
        for (int o = 32; o > 0; o >>= 1) {
            de += __shfl_xor(de, o);
            dn += __shfl_xor(dn, o);
            dc += __shfl_xor(dc, o);
        }
        {   // edge layer: feature = ev
            float nm = fmaxf(me, de); float s = __expf(me - nm); float pr = __expf(de - nm);
            le = le * s + pr;
            ae.x = ae.x * s + pr * ev.x; ae.y = ae.y * s + pr * ev.y;
            ae.z = ae.z * s + pr * ev.z; ae.w = ae.w * s + pr * ev.w;
            me = nm;
        }
        {   // node layer: feature = sv
            float nm = fmaxf(mn, dn); float s = __expf(mn - nm); float pr = __expf(dn - nm);
            ln = ln * s + pr;
            an.x = an.x * s + pr * sv.x; an.y = an.y * s + pr * sv.y;
            an.z = an.z * s + pr * sv.z; an.w = an.w * s + pr * sv.w;
            mn = nm;
        }
        {   // comp layer: feature = cv
            float nm = fmaxf(mc, dc); float s = __expf(mc - nm); float pr = __expf(dc - nm);
            lc = lc * s + pr;
            ac.x = ac.x * s + pr * cv.x; ac.y = ac.y * s + pr * cv.y;
            ac.z = ac.z * s + pr * cv.z; ac.w = ac.w * s + pr * cv.w;
            mc = nm;
        }
    }
    float ie = (le > 0.f) ? 1.0f / le : 0.f;
    float in_ = (ln > 0.f) ? 1.0f / ln : 0.f;
    float ic = (lc > 0.f) ? 1.0f / lc : 0.f;
    ((ushort4*)(agg_e + (size_t)d * H))[lane] = pack4(ae, ie);
    ((ushort4*)(agg_n + (size_t)d * H))[lane] = pack4(an, in_);
    ((ushort4*)(agg_c + (size_t)d * H))[lane] = pack4(ac, ic);
}

// ---------------- fused multi-layer GEMM epilogue ----------------
// out[r, :] = base[r, :] + sum_l tanh(A_l[r, :] @ W_l)      (or raw if !do_tanh)
// 64 rows/block, 4 waves; each wave: 64 rows x 64 cols of 16x16x32 bf16 MFMA tiles
__global__ __launch_bounds__(256, 2) void gemm_kernel(
    const u16* __restrict__ A0, const u16* __restrict__ A1, const u16* __restrict__ A2,
    const u16* __restrict__ W0, const u16* __restrict__ W1, const u16* __restrict__ W2,
    const float* __restrict__ base, float* __restrict__ out,
    int n_real, int n_layers, int do_tanh) {
    __shared__ u16 lA[64 * 264];  // row stride 264 shorts (528B) to dodge bank conflicts
    int tid = threadIdx.x;
    int lane = tid & 63;
    int wv = tid >> 6;     // wave 0..3 -> col block
    int m = lane & 15;
    int quad = lane >> 4;
    int r0 = blockIdx.x * 64;

    float outacc[4][4][4];
#pragma unroll
    for (int rt = 0; rt < 4; ++rt)
#pragma unroll
        for (int ct = 0; ct < 4; ++ct) {
            int grow = r0 + rt * 16 + quad * 4;
            int gcol = wv * 64 + ct * 16 + m;
#pragma unroll
            for (int r = 0; r < 4; ++r) {
                float v = 0.f;
                if (base != nullptr && (grow + r) < n_real) v = base[(size_t)(grow + r) * H + gcol];
                outacc[rt][ct][r] = v;
            }
        }

    for (int l = 0; l < n_layers; ++l) {
        const u16* Al = (l == 0) ? A0 : (l == 1) ? A1 : A2;
        const u16* Wl = (l == 0) ? W0 : (l == 1) ? W1 : W2;
        __syncthreads();
#pragma unroll
        for (int it = 0; it < 8; ++it) {
            int row = it * 8 + (tid >> 5);
            int seg = tid & 31;
            uint4 v = make_uint4(0, 0, 0, 0);
            int gr = r0 + row;
            if (gr < n_real) v = *(const uint4*)(Al + (size_t)gr * H + seg * 8);
            *(uint4*)(&lA[row * 264 + seg * 8]) = v;
        }
        __syncthreads();

        floatx4 lacc[4][4];
#pragma unroll
        for (int rt = 0; rt < 4; ++rt)
#pragma unroll
            for (int ct = 0; ct < 4; ++ct)
#pragma unroll
                for (int r = 0; r < 4; ++r) lacc[rt][ct][r] = 0.f;

#pragma unroll
        for (int ks = 0; ks < 8; ++ks) {
            bf16x8 af[4], bfr[4];
#pragma unroll
            for (int rt = 0; rt < 4; ++rt)
                af[rt] = *(const bf16x8*)(&lA[(rt * 16 + m) * 264 + ks * 32 + quad * 8]);
#pragma unroll
            for (int ct = 0; ct < 4; ++ct)
                bfr[ct] = *(const bf16x8*)(Wl + (((size_t)(wv * 4 + ct) * 8 + ks) * 64 + lane) * 8);
#pragma unroll
            for (int rt = 0; rt < 4; ++rt)
#pragma unroll
                for (int ct = 0; ct < 4; ++ct)
                    lacc[rt][ct] = __builtin_amdgcn_mfma_f32_16x16x32_bf16(
                        af[rt], bfr[ct], lacc[rt][ct], 0, 0, 0);
        }

#pragma unroll
        for (int rt = 0; rt < 4; ++rt)
#pragma unroll
            for (int ct = 0; ct < 4; ++ct)
#pragma unroll
                for (int r = 0; r < 4; ++r) {
                    float v = lacc[rt][ct][r];
                    outacc[rt][ct][r] += do_tanh ? tanhf(v) : v;
                }
    }

#pragma unroll
    for (int rt = 0; rt < 4; ++rt)
#pragma unroll
        for (int ct = 0; ct < 4; ++ct) {
            int grow = r0 + rt * 16 + quad * 4;
            int gcol = wv * 64 + ct * 16 + m;
#pragma unroll
            for (int r = 0; r < 4; ++r)
                if ((grow + r) < n_real) out[(size_t)(grow + r) * H + gcol] = outacc[rt][ct][r];
        }
}

// ---------------- launch ----------------

extern "C" void kernel_launch(void* const* d_in, const int* in_sizes, int n_in,
                              void* d_out, int out_size, void* d_ws, size_t ws_size,
                              hipStream_t stream) {
    (void)in_sizes; (void)n_in; (void)out_size; (void)ws_size;
    const float* ent    = (const float*)d_in[0];
    const float* rel    = (const float*)d_in[1];
    const float* w_edge = (const float*)d_in[2];
    const float* w_node = (const float*)d_in[3];
    const float* w_comp = (const float*)d_in[4];
    const float* rel_w  = (const float*)d_in[5];
    const int* src      = (const int*)d_in[6];
    const int* dst      = (const int*)d_in[7];
    const int* rel_id   = (const int*)d_in[8];
    const int* node_id  = (const int*)d_in[9];

    char* wsb = (char*)d_ws;
    size_t o = 0;
    auto alloc = [&](size_t bytes) -> char* {
        char* p = wsb + o;
        o = (o + bytes + 255) & ~(size_t)255;
        return p;
    };
    int* counts  = (int*)alloc((size_t)N_ENT * 4);
    int* offsets = (int*)alloc((size_t)(N_ENT + 1) * 4);
    int* sorted  = (int*)alloc((size_t)E_EDGES * 4);
    u16* agg_e   = (u16*)alloc((size_t)N_ENT * H * 2);
    u16* agg_n   = (u16*)alloc((size_t)N_ENT * H * 2);
    u16* agg_c   = (u16*)alloc((size_t)N_ENT * H * 2);
    u16* wswz    = (u16*)alloc((size_t)4 * H * H * 2);
    u16* relbf   = (u16*)alloc((size_t)N_REL2 * H * 2);

    float* out_ent = (float*)d_out;
    float* out_rel = out_ent + (size_t)N_ENT * H;

    hipMemsetAsync(counts, 0, (size_t)N_ENT * 4, stream);
    hist_kernel<<<(E_EDGES + 255) / 256, 256, 0, stream>>>(dst, counts);
    scan_kernel<<<1, 1024, 0, stream>>>(counts, offsets);
    place_kernel<<<(E_EDGES + 255) / 256, 256, 0, stream>>>(dst, offsets, counts, sorted);
    swz_kernel<<<(4 * H * H + 255) / 256, 256, 0, stream>>>(w_edge, w_node, w_comp, rel_w, wswz);
    relbf_kernel<<<(N_REL2 * H + 255) / 256, 256, 0, stream>>>(rel, relbf);
    scatter_kernel<<<(N_ENT + 3) / 4, 256, 0, stream>>>(ent, rel, src, rel_id, node_id,
                                                        offsets, sorted, agg_e, agg_n, agg_c);
    gemm_kernel<<<(N_ENT + 63) / 64, 256, 0, stream>>>(agg_e, agg_n, agg_c,
                                                       wswz, wswz + H * H, wswz + 2 * H * H,
                                                       ent, out_ent, N_ENT, 3, 1);
    gemm_kernel<<<(N_REL2 + 63) / 64, 256, 0, stream>>>(relbf, relbf, relbf,
                                                        wswz + 3 * H * H, wswz + 3 * H * H, wswz + 3 * H * H,
                                                        nullptr, out_rel, N_REL2, 1, 0);
}

// Round 2
// 650.855 us; speedup vs baseline: 1.1012x; 1.1012x over previous
//
#include <hip/hip_runtime.h>
#include <hip/hip_bf16.h>

#define N_ENT  100000
#define N_REL2 1000
#define H      256
#define E_EDGES 320000
#define N_TILES  6250      // N_ENT/16 exactly
#define REL_TILES 64       // ceil(1000/16)=63, pad to 64
#define TILE_SH 4096       // shorts per 16-row tile (16*256)

typedef unsigned short u16;
typedef short bf16x8 __attribute__((ext_vector_type(8)));
typedef float floatx4 __attribute__((ext_vector_type(4)));

__device__ __forceinline__ u16 f2bf(float f) {
    unsigned x = __float_as_uint(f);
    unsigned r = (x + 0x7fffu + ((x >> 16) & 1u)) >> 16;  // RNE
    return (u16)r;
}

__device__ __forceinline__ ushort4 pack4(float4 v, float s) {
    return make_ushort4(f2bf(v.x * s), f2bf(v.y * s), f2bf(v.z * s), f2bf(v.w * s));
}

__device__ __forceinline__ float fast_tanh(float x) {
    // tanh(x) = 1 - 2/(e^{2x}+1); v_exp + v_rcp, ~4 instrs, err << bf16 ulp
    float e = __expf(2.0f * x);
    return 1.0f - 2.0f * __builtin_amdgcn_rcpf(e + 1.0f);
}

__device__ __forceinline__ void async16(u16* lds, const u16* g) {
    __builtin_amdgcn_global_load_lds(
        (const __attribute__((address_space(1))) void*)g,
        (__attribute__((address_space(3))) void*)lds, 16, 0, 0);
}

// ---------------- CSR build ----------------

__global__ void hist_kernel(const int* __restrict__ dst, int* __restrict__ counts) {
    int i = blockIdx.x * blockDim.x + threadIdx.x;
    if (i < E_EDGES) atomicAdd(&counts[dst[i]], 1);
}

// hierarchical scan: 98 blocks x 1024
__global__ void scan1_kernel(const int* __restrict__ counts, int* __restrict__ offsets,
                             int* __restrict__ bsum) {
    __shared__ int buf[1024];
    int t = threadIdx.x, i = blockIdx.x * 1024 + t;
    int v = (i < N_ENT) ? counts[i] : 0;
    int acc = v;
    buf[t] = acc;
    __syncthreads();
    for (int off = 1; off < 1024; off <<= 1) {
        int u = (t >= off) ? buf[t - off] : 0;
        __syncthreads();
        acc += u;
        buf[t] = acc;
        __syncthreads();
    }
    if (i < N_ENT) offsets[i] = acc - v;  // exclusive within block
    if (t == 1023) bsum[blockIdx.x] = acc;
}

__global__ void scan2_kernel(int* __restrict__ bsum, int* __restrict__ offsets) {
    __shared__ int s[128];
    int t = threadIdx.x;
    s[t] = (t < 98) ? bsum[t] : 0;
    __syncthreads();
    if (t == 0) {
        int run = 0;
        for (int b = 0; b < 98; ++b) { int x = s[b]; s[b] = run; run += x; }
        offsets[N_ENT] = run;
    }
    __syncthreads();
    if (t < 98) bsum[t] = s[t];
}

__global__ void scan3_kernel(int* __restrict__ offsets, const int* __restrict__ bsum) {
    int i = blockIdx.x * 1024 + threadIdx.x;
    if (i < N_ENT && blockIdx.x > 0) offsets[i] += bsum[blockIdx.x];
}

__global__ void place_kernel(const int* __restrict__ dst, const int* __restrict__ offsets,
                             int* __restrict__ counts, int* __restrict__ sorted) {
    int i = blockIdx.x * blockDim.x + threadIdx.x;
    if (i < E_EDGES) {
        int d = dst[i];
        int old = atomicSub(&counts[d], 1);
        sorted[offsets[d] + old - 1] = i;
    }
}

// ---------------- weight prep ----------------
// B-fragment order for mfma_f32_16x16x32_bf16 (verified R1):
// dst[((ntile*8+kstep)*64+lane)*8+j] = bf16(W[kstep*32+(lane>>4)*8+j][ntile*16+(lane&15)])
__global__ void swz_kernel(const float* __restrict__ w0, const float* __restrict__ w1,
                           const float* __restrict__ w2, const float* __restrict__ w3,
                           u16* __restrict__ dstp) {
    int t = blockIdx.x * blockDim.x + threadIdx.x;
    if (t >= 4 * H * H) return;
    int mat = t >> 16;
    int r = t & 65535;
    int j = r & 7, lane = (r >> 3) & 63, kstep = (r >> 9) & 7, ntile = r >> 12;
    int k = kstep * 32 + (lane >> 4) * 8 + j;
    int n = ntile * 16 + (lane & 15);
    const float* W = (mat == 0) ? w0 : (mat == 1) ? w1 : (mat == 2) ? w2 : w3;
    dstp[t] = f2bf(W[k * H + n]);
}

// rel_emb -> bf16 in A-fragment-tiled layout:
// addr = ((tile*8+ks)*64 + lane)*8 + j ; row=tile*16+(lane&15), k=ks*32+(lane>>4)*8+j
__global__ void relbf_kernel(const float* __restrict__ rel, u16* __restrict__ out) {
    int t = blockIdx.x * blockDim.x + threadIdx.x;
    if (t >= REL_TILES * TILE_SH) return;
    int j = t & 7, lane = (t >> 3) & 63, ks = (t >> 9) & 7, tile = t >> 12;
    int m = lane & 15, quad = lane >> 4;
    int row = tile * 16 + m, k = ks * 32 + quad * 8 + j;
    float v = (row < N_REL2) ? rel[row * H + k] : 0.f;
    out[t] = f2bf(v);
}

// ---------------- fused per-dst scores + softmax + segment-sum ----------------
// one wave per destination; 16 waves/block cover one 16-row output tile
__global__ void scatter_kernel(const float* __restrict__ ent, const float* __restrict__ rel,
                               const int* __restrict__ src, const int* __restrict__ rel_id,
                               const int* __restrict__ node_id,
                               const int* __restrict__ offsets, const int* __restrict__ sorted,
                               u16* __restrict__ agg_e, u16* __restrict__ agg_n,
                               u16* __restrict__ agg_c) {
    int d = blockIdx.x * 16 + (threadIdx.x >> 6);
    int lane = threadIdx.x & 63;
    if (d >= N_ENT) return;
    int nid = node_id[d];
    float4 hd = ((const float4*)(ent + (size_t)nid * H))[lane];
    int p0 = offsets[d], p1 = offsets[d + 1];
    float me = -INFINITY, mn = -INFINITY, mc = -INFINITY;
    float le = 0.f, ln = 0.f, lc = 0.f;
    float4 ae = make_float4(0, 0, 0, 0), an = make_float4(0, 0, 0, 0), ac = make_float4(0, 0, 0, 0);

    for (int pc = p0; pc < p1; pc += 4) {
        int cnt = p1 - pc; if (cnt > 4) cnt = 4;
        int sid[4], rid[4];
#pragma unroll
        for (int j = 0; j < 4; ++j) if (j < cnt) {
            int ei = sorted[pc + j];
            sid[j] = src[ei];
            rid[j] = rel_id[ei];
        }
#pragma unroll
        for (int j = 0; j < 4; ++j) if (j < cnt) sid[j] = node_id[sid[j]];
        float4 ev[4], sv[4];
#pragma unroll
        for (int j = 0; j < 4; ++j) if (j < cnt) {
            ev[j] = ((const float4*)(rel + (size_t)rid[j] * H))[lane];
            sv[j] = ((const float4*)(ent + (size_t)sid[j] * H))[lane];
        }
#pragma unroll
        for (int j = 0; j < 4; ++j) if (j < cnt) {
            float4 e4 = ev[j], s4 = sv[j];
            float4 c4 = make_float4(e4.x * s4.x, e4.y * s4.y, e4.z * s4.z, e4.w * s4.w);
            float de = e4.x * hd.x + e4.y * hd.y + e4.z * hd.z + e4.w * hd.w;
            float dn = s4.x * hd.x + s4.y * hd.y + s4.z * hd.z + s4.w * hd.w;
            float dc = c4.x * hd.x + c4.y * hd.y + c4.z * hd.z + c4.w * hd.w;
#pragma unroll
            for (int o = 32; o > 0; o >>= 1) {
                de += __shfl_xor(de, o);
                dn += __shfl_xor(dn, o);
                dc += __shfl_xor(dc, o);
            }
            { float nm = fmaxf(me, de); float s = __expf(me - nm); float pr = __expf(de - nm);
              le = le * s + pr;
              ae.x = ae.x * s + pr * e4.x; ae.y = ae.y * s + pr * e4.y;
              ae.z = ae.z * s + pr * e4.z; ae.w = ae.w * s + pr * e4.w; me = nm; }
            { float nm = fmaxf(mn, dn); float s = __expf(mn - nm); float pr = __expf(dn - nm);
              ln = ln * s + pr;
              an.x = an.x * s + pr * s4.x; an.y = an.y * s + pr * s4.y;
              an.z = an.z * s + pr * s4.z; an.w = an.w * s + pr * s4.w; mn = nm; }
            { float nm = fmaxf(mc, dc); float s = __expf(mc - nm); float pr = __expf(dc - nm);
              lc = lc * s + pr;
              ac.x = ac.x * s + pr * c4.x; ac.y = ac.y * s + pr * c4.y;
              ac.z = ac.z * s + pr * c4.z; ac.w = ac.w * s + pr * c4.w; mc = nm; }
        }
    }
    float ie = (le > 0.f) ? 1.0f / le : 0.f;
    float in_ = (ln > 0.f) ? 1.0f / ln : 0.f;
    float ic = (lc > 0.f) ? 1.0f / lc : 0.f;
    // store into A-fragment-tiled layout: element (d, k=4*lane..4*lane+3)
    size_t tile = (size_t)(d >> 4); int m = d & 15;
    int ks = lane >> 3, quad = (lane >> 1) & 3, j0 = (lane & 1) * 4;
    size_t addr = ((tile * 8 + ks) * 64 + quad * 16 + m) * 8 + j0;
    *(ushort4*)(agg_e + addr) = pack4(ae, ie);
    *(ushort4*)(agg_n + addr) = pack4(an, in_);
    *(ushort4*)(agg_c + addr) = pack4(ac, ic);
}

// ---------------- fused multi-layer GEMM epilogue ----------------
// out[r,:] = base[r,:] + sum_l tanh(A_l[r,:] @ W_l)   (raw if !do_tanh)
// 64 rows x 256 cols per block, 4 waves; A async-staged to LDS, layer ping-pong
__global__ __launch_bounds__(256, 2) void gemm_kernel(
    const u16* __restrict__ A0, const u16* __restrict__ A1, const u16* __restrict__ A2,
    const u16* __restrict__ W0, const u16* __restrict__ W1, const u16* __restrict__ W2,
    const float* __restrict__ base, float* __restrict__ out,
    int n_real, int n_layers, int do_tanh) {
    __shared__ u16 lA[2][16384];  // 2 x 32KB, fragment-tiled: rt*4096 + ks*512 + lane*8
    int tid = threadIdx.x;
    int lane = tid & 63;
    int wv = tid >> 6;
    int m = lane & 15;
    int quad = lane >> 4;
    int r0 = blockIdx.x * 64;
    const u16* As[3] = { A0, A1, A2 };
    const u16* Ws[3] = { W0, W1, W2 };

    float outacc[4][4][4];
#pragma unroll
    for (int rt = 0; rt < 4; ++rt)
#pragma unroll
        for (int ct = 0; ct < 4; ++ct) {
            int grow = r0 + rt * 16 + quad * 4;
            int gcol = wv * 64 + ct * 16 + m;
#pragma unroll
            for (int r = 0; r < 4; ++r) {
                float v = 0.f;
                if (base != nullptr && (grow + r) < n_real) v = base[(size_t)(grow + r) * H + gcol];
                outacc[rt][ct][r] = v;
            }
        }

    // stage layer 0 into buf 0 (linear 32KB copy, async to LDS)
    {
        const u16* gsrc = As[0] + (size_t)blockIdx.x * 4 * TILE_SH;
#pragma unroll
        for (int rnd = 0; rnd < 8; ++rnd) {
            int off8 = (rnd * 256 + tid) * 8;
            async16(&lA[0][off8], gsrc + off8);
        }
    }

    for (int l = 0; l < n_layers; ++l) {
        __syncthreads();  // buf[l&1] staged; prev layer's ds_reads complete
        if (l + 1 < n_layers) {
            const u16* gsrc = As[l + 1] + (size_t)blockIdx.x * 4 * TILE_SH;
            u16* dstb = lA[(l + 1) & 1];
#pragma unroll
            for (int rnd = 0; rnd < 8; ++rnd) {
                int off8 = (rnd * 256 + tid) * 8;
                async16(&dstb[off8], gsrc + off8);
            }
        }
        const u16* lbuf = lA[l & 1];
        const u16* Wl = Ws[l];

        floatx4 lacc[4][4];
#pragma unroll
        for (int rt = 0; rt < 4; ++rt)
#pragma unroll
            for (int ct = 0; ct < 4; ++ct)
#pragma unroll
                for (int r = 0; r < 4; ++r) lacc[rt][ct][r] = 0.f;

#pragma unroll
        for (int ks = 0; ks < 8; ++ks) {
            bf16x8 af[4], bfr[4];
#pragma unroll
            for (int rt = 0; rt < 4; ++rt)
                af[rt] = *(const bf16x8*)(lbuf + rt * 4096 + ks * 512 + lane * 8);
#pragma unroll
            for (int ct = 0; ct < 4; ++ct)
                bfr[ct] = *(const bf16x8*)(Wl + (((size_t)(wv * 4 + ct) * 8 + ks) * 64 + lane) * 8);
#pragma unroll
            for (int rt = 0; rt < 4; ++rt)
#pragma unroll
                for (int ct = 0; ct < 4; ++ct)
                    lacc[rt][ct] = __builtin_amdgcn_mfma_f32_16x16x32_bf16(
                        af[rt], bfr[ct], lacc[rt][ct], 0, 0, 0);
        }

#pragma unroll
        for (int rt = 0; rt < 4; ++rt)
#pragma unroll
            for (int ct = 0; ct < 4; ++ct)
#pragma unroll
                for (int r = 0; r < 4; ++r) {
                    float v = lacc[rt][ct][r];
                    outacc[rt][ct][r] += do_tanh ? fast_tanh(v) : v;
                }
    }

#pragma unroll
    for (int rt = 0; rt < 4; ++rt)
#pragma unroll
        for (int ct = 0; ct < 4; ++ct) {
            int grow = r0 + rt * 16 + quad * 4;
            int gcol = wv * 64 + ct * 16 + m;
#pragma unroll
            for (int r = 0; r < 4; ++r)
                if ((grow + r) < n_real) out[(size_t)(grow + r) * H + gcol] = outacc[rt][ct][r];
        }
}

// ---------------- launch ----------------

extern "C" void kernel_launch(void* const* d_in, const int* in_sizes, int n_in,
                              void* d_out, int out_size, void* d_ws, size_t ws_size,
                              hipStream_t stream) {
    (void)in_sizes; (void)n_in; (void)out_size; (void)ws_size;
    const float* ent    = (const float*)d_in[0];
    const float* rel    = (const float*)d_in[1];
    const float* w_edge = (const float*)d_in[2];
    const float* w_node = (const float*)d_in[3];
    const float* w_comp = (const float*)d_in[4];
    const float* rel_w  = (const float*)d_in[5];
    const int* src      = (const int*)d_in[6];
    const int* dst      = (const int*)d_in[7];
    const int* rel_id   = (const int*)d_in[8];
    const int* node_id  = (const int*)d_in[9];

    char* wsb = (char*)d_ws;
    size_t o = 0;
    auto alloc = [&](size_t bytes) -> char* {
        char* p = wsb + o;
        o = (o + bytes + 255) & ~(size_t)255;
        return p;
    };
    int* counts  = (int*)alloc((size_t)N_ENT * 4);
    int* offsets = (int*)alloc((size_t)(N_ENT + 1) * 4);
    int* bsum    = (int*)alloc(128 * 4);
    int* sorted  = (int*)alloc((size_t)E_EDGES * 4);
    u16* agg_e   = (u16*)alloc((size_t)N_TILES * TILE_SH * 2);
    u16* agg_n   = (u16*)alloc((size_t)N_TILES * TILE_SH * 2);
    u16* agg_c   = (u16*)alloc((size_t)N_TILES * TILE_SH * 2);
    u16* wswz    = (u16*)alloc((size_t)4 * H * H * 2);
    u16* relbf   = (u16*)alloc((size_t)REL_TILES * TILE_SH * 2);
    (void)alloc(65536);  // overrun pad for tail-block A staging reads

    float* out_ent = (float*)d_out;
    float* out_rel = out_ent + (size_t)N_ENT * H;

    hipMemsetAsync(counts, 0, (size_t)N_ENT * 4, stream);
    hist_kernel<<<(E_EDGES + 255) / 256, 256, 0, stream>>>(dst, counts);
    scan1_kernel<<<98, 1024, 0, stream>>>(counts, offsets, bsum);
    scan2_kernel<<<1, 128, 0, stream>>>(bsum, offsets);
    scan3_kernel<<<98, 1024, 0, stream>>>(offsets, bsum);
    place_kernel<<<(E_EDGES + 255) / 256, 256, 0, stream>>>(dst, offsets, counts, sorted);
    swz_kernel<<<(4 * H * H + 255) / 256, 256, 0, stream>>>(w_edge, w_node, w_comp, rel_w, wswz);
    relbf_kernel<<<(REL_TILES * TILE_SH + 255) / 256, 256, 0, stream>>>(rel, relbf);
    scatter_kernel<<<N_TILES, 1024, 0, stream>>>(ent, rel, src, rel_id, node_id,
                                                 offsets, sorted, agg_e, agg_n, agg_c);
    gemm_kernel<<<(N_ENT + 63) / 64, 256, 0, stream>>>(agg_e, agg_n, agg_c,
                                                       wswz, wswz + H * H, wswz + 2 * H * H,
                                                       ent, out_ent, N_ENT, 3, 1);
    gemm_kernel<<<(N_REL2 + 63) / 64, 256, 0, stream>>>(relbf, relbf, relbf,
                                                        wswz + 3 * H * H, wswz + 3 * H * H, wswz + 3 * H * H,
                                                        nullptr, out_rel, N_REL2, 1, 0);
}